// Round 5
// baseline (422.851 us; speedup 1.0000x reference)
//
#include <hip/hip_runtime.h>
#include <cstdint>
#include <cstddef>

#define DD 512
#define TT 16384
#define CC 8192
#define SPLITC 16
#define EPS_DIV 1e-6f
#define EPS_NORM 1e-12f
#define EPS_PD 1e-6f

typedef _Float16 half8 __attribute__((ext_vector_type(8)));
typedef _Float16 half4 __attribute__((ext_vector_type(4)));
typedef float floatx4 __attribute__((ext_vector_type(4)));

// async global->LDS, 16B per lane; lds base must be wave-uniform
#define GLDS16(g, l) __builtin_amdgcn_global_load_lds( \
    (const __attribute__((address_space(1))) void*)(g), \
    (__attribute__((address_space(3))) void*)(l), 16, 0, 0)

// ---------------- prep: split cb and W fp32 -> (hi|lo) fp16 [row][1024] ----------------
__global__ __launch_bounds__(256) void k_prep(
    const float* __restrict__ cb, const float* __restrict__ W,
    _Float16* __restrict__ cbs, _Float16* __restrict__ Ws) {
  const int b = blockIdx.x;
  const float* src;
  _Float16* dst;
  int row;
  if (b < CC / 2) {
    row = b * 2 + (threadIdx.x >> 7);
    src = cb; dst = cbs;
  } else {
    row = (b - CC / 2) * 2 + (threadIdx.x >> 7);
    src = W; dst = Ws;
  }
  const int col = (threadIdx.x & 127) * 4;
  float4 v = *(const float4*)(src + (size_t)row * DD + col);
  half4 h, l;
  h.x = (_Float16)v.x; l.x = (_Float16)(v.x - (float)h.x);
  h.y = (_Float16)v.y; l.y = (_Float16)(v.y - (float)h.y);
  h.z = (_Float16)v.z; l.z = (_Float16)(v.z - (float)h.z);
  h.w = (_Float16)v.w; l.w = (_Float16)(v.w - (float)h.w);
  *(half4*)(dst + (size_t)row * 1024 + col) = h;
  *(half4*)(dst + (size_t)row * 1024 + 512 + col) = l;
}

// ---------------- imp = cb @ W^T via split-fp16 3-pass MFMA ----------------
// 128x128 tile, 4 waves 2x2, BK=64 dbuf; coalesced LDS-transpose epilogue
// writes imp fp32 + ih fp16.
__global__ __launch_bounds__(256) void k_gemm_mfma(
    const _Float16* __restrict__ cbs, const _Float16* __restrict__ Ws,
    float* __restrict__ imp, _Float16* __restrict__ ih) {
  __shared__ __align__(16) char smem[65536];  // A0,B0,A1,B1 @16KB; Csh 64KB overlaps
  const int tid = threadIdx.x;
  const int w = tid >> 6, lane = tid & 63;
  const int quad = lane >> 4, l15 = lane & 15;
  const int wm = (w & 1) * 64, wn = (w >> 1) * 64;
  const int c0 = blockIdx.x * 128;
  const int n0 = blockIdx.y * 128;

  const int srow8 = lane >> 3;
  const int scol = ((lane & 7) ^ srow8) << 3;  // halfs, XOR-swizzled col block
  size_t arow[4], brow[4];
#pragma unroll
  for (int j = 0; j < 4; ++j) {
    arow[j] = (size_t)(c0 + j * 32 + w * 8 + srow8) * 1024 + scol;
    brow[j] = (size_t)(n0 + j * 32 + w * 8 + srow8) * 1024 + scol;
  }
  int aoff[4], boff[4];
#pragma unroll
  for (int i = 0; i < 4; ++i) {
    aoff[i] = ((wm + i * 16 + l15) * 64 + ((quad ^ (l15 & 7)) << 3)) * 2;
    boff[i] = ((wn + i * 16 + l15) * 64 + ((quad ^ (l15 & 7)) << 3)) * 2;
  }

  auto stage = [&](int buf, int ak, int bk) {
    char* ab = smem + buf * 32768;
    char* bb = ab + 16384;
#pragma unroll
    for (int j = 0; j < 4; ++j) {
      GLDS16(cbs + arow[j] + ak, (_Float16*)ab + (j * 32 + w * 8) * 64);
      GLDS16(Ws  + brow[j] + bk, (_Float16*)bb + (j * 32 + w * 8) * 64);
    }
  };

  floatx4 acc[4][4] = {};
  stage(0, 0, 0);
#pragma unroll 2
  for (int it = 0; it < 24; ++it) {   // 3 passes x 8 k-steps
    __syncthreads();
    if (it < 23) {
      const int n = it + 1;
      const int p = n >> 3, kk = n & 7;
      const int ak = ((p == 2) ? 512 : 0) + kk * 64;
      const int bk = ((p == 1) ? 512 : 0) + kk * 64;
      stage(n & 1, ak, bk);
    }
    const char* ab = smem + (it & 1) * 32768;
    const char* bb = ab + 16384;
#pragma unroll
    for (int ks = 0; ks < 2; ++ks) {
      const int kx = ks * 64;
      half8 a[4], b[4];
#pragma unroll
      for (int mi = 0; mi < 4; ++mi)
        a[mi] = *(const half8*)(ab + (aoff[mi] ^ kx));
#pragma unroll
      for (int ni = 0; ni < 4; ++ni)
        b[ni] = *(const half8*)(bb + (boff[ni] ^ kx));
#pragma unroll
      for (int mi = 0; mi < 4; ++mi)
#pragma unroll
        for (int ni = 0; ni < 4; ++ni)
          acc[mi][ni] = __builtin_amdgcn_mfma_f32_16x16x32_f16(
              a[mi], b[ni], acc[mi][ni], 0, 0, 0);
    }
  }
  // epilogue: C fragments -> swizzled LDS tile -> coalesced global stores
  __syncthreads();
  float* Csh = (float*)smem;  // [128][128], col ^ ((row&7)<<2)
#pragma unroll
  for (int mi = 0; mi < 4; ++mi)
#pragma unroll
    for (int r = 0; r < 4; ++r) {
      const int row = wm + mi * 16 + quad * 4 + r;
      const int key = (row & 7) << 2;
#pragma unroll
      for (int ni = 0; ni < 4; ++ni) {
        const int col = wn + ni * 16 + l15;
        Csh[row * 128 + (col ^ key)] = acc[mi][ni][r];
      }
    }
  __syncthreads();
#pragma unroll
  for (int i = 0; i < 16; ++i) {
    const int row = (tid >> 5) * 16 + i;
    const int col = (tid & 31) * 4;
    const int key = (row & 7) << 2;
    const float4 v = *(const float4*)&Csh[row * 128 + (col ^ key)];
    *(float4*)&imp[(size_t)(c0 + row) * DD + n0 + col] = v;
    half4 h;
    h.x = (_Float16)v.x; h.y = (_Float16)v.y;
    h.z = (_Float16)v.z; h.w = (_Float16)v.w;
    *(half4*)&ih[(size_t)(c0 + row) * DD + n0 + col] = h;
  }
}

// ---------------- cast x -> fp16 AND per-code squared norms ----------------
__global__ __launch_bounds__(256) void k_cast_cnorm(
    const float* __restrict__ x, _Float16* __restrict__ xh,
    const float* __restrict__ imp, float* __restrict__ cnorm) {
  const int b = blockIdx.x;
  if (b < TT / 2) {
    const size_t base = (size_t)b * 1024 + threadIdx.x * 4;
    float4 v = *(const float4*)(x + base);
    half4 h;
    h.x = (_Float16)v.x; h.y = (_Float16)v.y;
    h.z = (_Float16)v.z; h.w = (_Float16)v.w;
    *(half4*)(xh + base) = h;
  } else {
    const int lane = threadIdx.x & 63;
    const int row = (b - TT / 2) * 4 + (threadIdx.x >> 6);
    const float* p = imp + (size_t)row * DD + lane * 8;
    float4 a = *(const float4*)p;
    float4 c = *(const float4*)(p + 4);
    float s = a.x * a.x + a.y * a.y + a.z * a.z + a.w * a.w +
              c.x * c.x + c.y * c.y + c.z * c.z + c.w * c.w;
#pragma unroll
    for (int m = 1; m < 64; m <<= 1) s += __shfl_xor(s, m);
    if (lane == 0) cnorm[row] = s;
  }
}

// ---------------- phase 1: fp16 hi.hi MFMA scores + per-row TOP-2 ----------------
// 128x128 tile, BK=32 dbuf (33KB LDS -> 3-4 blocks/CU), 4 c-tiles streamed as
// 64 continuous k-steps (one barrier each, no inter-tile pipeline drain).
// Swizzle for 64B rows: phys 16B-block = logical ^ ((row>>1)&3).
__global__ __launch_bounds__(256) void k_dist_top2(
    const _Float16* __restrict__ xh, const _Float16* __restrict__ ih,
    const float* __restrict__ cnorm,
    float* __restrict__ bval, int* __restrict__ bidx) {
  __shared__ __align__(16) char smem[33792];  // A0,B0 @8KB + A1,B1 @8KB; reduce overlaps
  const int tid = threadIdx.x;
  const int w = tid >> 6, lane = tid & 63;
  const int quad = lane >> 4, l15 = lane & 15;
  const int wm = (w & 1) * 64, wn = (w >> 1) * 64;
  const int r0 = blockIdx.x * 128;
  const int cb0 = blockIdx.y * 512;   // this block's 4 c-tiles

  const int srow = lane >> 2;                               // 0..15 within group
  const int scol = (((lane & 3) ^ ((lane >> 3) & 3)) << 3); // halfs, swizzled
  size_t aoffg[2];
  int browt[2], ldst[2];
#pragma unroll
  for (int j = 0; j < 2; ++j) {
    aoffg[j] = (size_t)(r0 + w * 32 + j * 16 + srow) * DD + scol;
    browt[j] = w * 32 + j * 16 + srow;
    ldst[j] = (w * 32 + j * 16) * 32;   // halfs
  }
  int aoff[4], boff[4];
#pragma unroll
  for (int i = 0; i < 4; ++i) {
    const int pb = quad ^ ((l15 >> 1) & 3);
    aoff[i] = ((wm + i * 16 + l15) * 32 + (pb << 3)) * 2;  // bytes
    boff[i] = ((wn + i * 16 + l15) * 32 + (pb << 3)) * 2;
  }

  auto stage = [&](int g) {
    const int buf = g & 1;
    const int ct = g >> 4, kk = g & 15;
    const int k0 = kk * 32;
    _Float16* ab = (_Float16*)(smem + buf * 16384);
    _Float16* bb = (_Float16*)(smem + buf * 16384 + 8192);
    const _Float16* bsrc = ih + (size_t)(cb0 + ct * 128) * DD;
#pragma unroll
    for (int j = 0; j < 2; ++j) {
      GLDS16(xh + aoffg[j] + k0, ab + ldst[j]);
      GLDS16(bsrc + (size_t)browt[j] * DD + scol + k0, bb + ldst[j]);
    }
  };

  float best[16];
  int bsti[16];
#pragma unroll
  for (int i = 0; i < 16; ++i) { best[i] = 3.4e38f; bsti[i] = 0; }
  floatx4 acc[4][4] = {};

  stage(0);
  for (int ct = 0; ct < 4; ++ct) {
#pragma unroll 4
    for (int kk = 0; kk < 16; ++kk) {
      const int g = ct * 16 + kk;
      __syncthreads();
      if (g < 63) stage(g + 1);
      const char* ab = smem + (g & 1) * 16384;
      const char* bb = ab + 8192;
      half8 a[4], b[4];
#pragma unroll
      for (int mi = 0; mi < 4; ++mi)
        a[mi] = *(const half8*)(ab + aoff[mi]);
#pragma unroll
      for (int ni = 0; ni < 4; ++ni)
        b[ni] = *(const half8*)(bb + boff[ni]);
#pragma unroll
      for (int mi = 0; mi < 4; ++mi)
#pragma unroll
        for (int ni = 0; ni < 4; ++ni)
          acc[mi][ni] = __builtin_amdgcn_mfma_f32_16x16x32_f16(
              a[mi], b[ni], acc[mi][ni], 0, 0, 0);
    }
    // fold c-tile (c ascends with ct,ni; strict < keeps lowest idx), reset acc
    const int cb1 = cb0 + ct * 128;
#pragma unroll
    for (int ni = 0; ni < 4; ++ni) {
      const int c = cb1 + wn + ni * 16 + l15;
      const float nn = cnorm[c];
#pragma unroll
      for (int mi = 0; mi < 4; ++mi)
#pragma unroll
        for (int r = 0; r < 4; ++r) {
          const float v = fmaf(-2.0f, acc[mi][ni][r], nn);
          const int s = mi * 4 + r;
          if (v < best[s]) { best[s] = v; bsti[s] = c; }
          if (ni == 3) acc[mi][3][r] = 0.0f;
        }
      if (ni < 3)
#pragma unroll
        for (int mi = 0; mi < 4; ++mi) acc[mi][ni] = (floatx4){0.f, 0.f, 0.f, 0.f};
    }
  }
  // per-row top-2 over 32 entries (LDS scratch overlaps tile buffers)
  __syncthreads();
  float* rv = (float*)smem;            // [128][33]
  int* ri = (int*)(smem + 16896);      // [128][33]
  const int e = (w >> 1) * 16 + l15;   // 0..31
#pragma unroll
  for (int mi = 0; mi < 4; ++mi)
#pragma unroll
    for (int r = 0; r < 4; ++r) {
      const int row = wm + mi * 16 + quad * 4 + r;
      rv[row * 33 + e] = best[mi * 4 + r];
      ri[row * 33 + e] = bsti[mi * 4 + r];
    }
  __syncthreads();
  if (tid < 128) {
    float v1 = 3.4e38f, v2 = 3.4e38f;
    int i1 = 0x7fffffff, i2 = 0x7fffffff;
#pragma unroll
    for (int t = 0; t < 32; ++t) {
      const float v = rv[tid * 33 + t];
      const int i = ri[tid * 33 + t];
      if (v < v1 || (v == v1 && i < i1)) {
        v2 = v1; i2 = i1; v1 = v; i1 = i;
      } else if (v < v2 || (v == v2 && i < i2)) {
        v2 = v; i2 = i;
      }
    }
    const size_t o = ((size_t)blockIdx.y * TT + r0 + tid) * 2;
    bval[o] = v1; bval[o + 1] = v2;
    bidx[o] = i1; bidx[o + 1] = i2;
  }
}

// ---------------- epilogue: butterfly top-2 merge, exact rescore, rotation ----------------
__global__ __launch_bounds__(256) void k_epilogue(
    const float* __restrict__ x, const float* __restrict__ imp,
    const float* __restrict__ cnorm,
    const float* __restrict__ bval, const int* __restrict__ bidx,
    float* __restrict__ outq, float* __restrict__ outidx,
    float* __restrict__ rloss) {
  const int lane = threadIdx.x & 63;
  const int row = blockIdx.x * 4 + (threadIdx.x >> 6);
  // lane (lane&31) -> entry (split=(lane>>1)&15, h=lane&1); upper 32 lanes mirror
  // lower, so 5 butterfly stages converge all 64 lanes to the global top-2.
  const size_t o = ((size_t)((lane >> 1) & 15) * TT + row) * 2 + (lane & 1);
  float v1 = bval[o], v2 = 3.4e38f;
  int i1 = bidx[o], i2 = 0x7fffffff;
#pragma unroll
  for (int m = 1; m < 32; m <<= 1) {
    const float w1 = __shfl_xor(v1, m), w2 = __shfl_xor(v2, m);
    const int j1 = __shfl_xor(i1, m), j2 = __shfl_xor(i2, m);
    if (w1 < v1 || (w1 == v1 && j1 < i1)) {
      if (v1 < w2 || (v1 == w2 && i1 < j2)) { v2 = v1; i2 = i1; }
      else { v2 = w2; i2 = j2; }
      v1 = w1; i1 = j1;
    } else {
      if (w1 < v2 || (w1 == v2 && j1 < i2)) { v2 = w1; i2 = j1; }
    }
  }
  // exact fp32 rescore of both candidates
  const float* xr = x + (size_t)row * DD + lane * 8;
  float e[8], qa[8], qb[8];
  *(float4*)&e[0] = *(const float4*)xr;
  *(float4*)&e[4] = *(const float4*)(xr + 4);
  const float* q1p = imp + (size_t)i1 * DD + lane * 8;
  const float* q2p = imp + (size_t)i2 * DD + lane * 8;
  *(float4*)&qa[0] = *(const float4*)q1p;
  *(float4*)&qa[4] = *(const float4*)(q1p + 4);
  *(float4*)&qb[0] = *(const float4*)q2p;
  *(float4*)&qb[4] = *(const float4*)(q2p + 4);
  float d1 = 0.f, d2 = 0.f;
#pragma unroll
  for (int k = 0; k < 8; ++k) {
    d1 = fmaf(e[k], qa[k], d1);
    d2 = fmaf(e[k], qb[k], d2);
  }
#pragma unroll
  for (int m = 1; m < 64; m <<= 1) {
    d1 += __shfl_xor(d1, m);
    d2 += __shfl_xor(d2, m);
  }
  const float s1 = fmaf(-2.0f, d1, cnorm[i1]);
  const float s2 = fmaf(-2.0f, d2, cnorm[i2]);
  const bool use2 = (s2 < s1) || (s2 == s1 && i2 < i1);
  const int idx = use2 ? i2 : i1;
  float q[8];
#pragma unroll
  for (int k = 0; k < 8; ++k) q[k] = use2 ? qb[k] : qa[k];

  float xx = 0.f, qq = 0.f, xq = 0.f, cl = 0.f;
#pragma unroll
  for (int k = 0; k < 8; ++k) {
    xx = fmaf(e[k], e[k], xx);
    qq = fmaf(q[k], q[k], qq);
    xq = fmaf(e[k], q[k], xq);
    float d = e[k] - q[k] + EPS_PD;
    cl = fmaf(d, d, cl);
  }
#pragma unroll
  for (int m = 1; m < 64; m <<= 1) {
    xx += __shfl_xor(xx, m);
    qq += __shfl_xor(qq, m);
    xq += __shfl_xor(xq, m);
    cl += __shfl_xor(cl, m);
  }
  const float nx = sqrtf(xx), nq = sqrtf(qq);
  const float dx = fmaxf(nx, EPS_DIV), dq = fmaxf(nq, EPS_DIV);
  const float uu = xx / (dx * dx);
  const float qq2 = qq / (dq * dq);
  const float uq = xq / (dx * dq);
  const float ss = uu + qq2 + 2.0f * uq;
  const float dn = fmaxf(sqrtf(ss), EPS_NORM);
  const float es = xx / dx + xq / dq;
  const float a = 2.0f * es / (dn * dn);
  const float b = 2.0f * (xx / dx);
  const float scale = nq / dx;

  float ov[8];
#pragma unroll
  for (int k = 0; k < 8; ++k) {
    const float qp = q[k] / dq;
    const float sk = e[k] / dx + qp;
    ov[k] = (e[k] - a * sk + b * qp) * scale;
  }
  float* op = outq + (size_t)row * DD + lane * 8;
  *(float4*)op = *(const float4*)&ov[0];
  *(float4*)(op + 4) = *(const float4*)&ov[4];
  if (lane == 0) {
    outidx[row] = (float)idx;
    rloss[row] = cl;
  }
}

// ---------------- final loss reduction (deterministic) ----------------
__global__ __launch_bounds__(256) void k_loss_final(
    const float* __restrict__ rloss, float* __restrict__ out) {
  __shared__ double red[256];
  const int tid = threadIdx.x;
  double s = 0.0;
  for (int i = tid; i < TT; i += 256) s += (double)rloss[i];
  red[tid] = s;
  __syncthreads();
  for (int st = 128; st > 0; st >>= 1) {
    if (tid < st) red[tid] += red[tid + st];
    __syncthreads();
  }
  if (tid == 0) out[0] = (float)(red[0] / (double)TT);
}

extern "C" void kernel_launch(void* const* d_in, const int* in_sizes, int n_in,
                              void* d_out, int out_size, void* d_ws, size_t ws_size,
                              hipStream_t stream) {
  const float* x  = (const float*)d_in[0];   // [TT, DD]
  const float* W  = (const float*)d_in[1];   // [DD, DD]
  const float* cb = (const float*)d_in[2];   // [CC, DD]
  float* out = (float*)d_out;

  // workspace (~45 MiB); xh aliases cbs (cbs dead after k_gemm_mfma)
  float* imp = (float*)d_ws;                             // CC*DD fp32 (16 MiB)
  _Float16* ih = (_Float16*)(imp + (size_t)CC * DD);     // CC*DD f16 (8 MiB)
  _Float16* cbs = ih + (size_t)CC * DD;                  // CC*1024 f16 (16 MiB)
  _Float16* xh = cbs;                                    // TT*DD f16 (alias)
  _Float16* Ws = cbs + (size_t)CC * 1024;                // DD*1024 f16 (1 MiB)
  float* cnorm = (float*)(Ws + (size_t)DD * 1024);       // CC
  float* bval  = cnorm + CC;                             // SPLITC*TT*2 (2 MiB)
  int*   bidx  = (int*)(bval + (size_t)SPLITC * TT * 2); // 2 MiB
  float* rloss = (float*)(bidx + (size_t)SPLITC * TT * 2);

  float* out_q    = out;
  float* out_idx  = out + (size_t)TT * DD;
  float* out_loss = out_idx + TT;

  k_prep<<<CC / 2 + DD / 2, 256, 0, stream>>>(cb, W, cbs, Ws);
  k_gemm_mfma<<<dim3(CC / 128, DD / 128), 256, 0, stream>>>(cbs, Ws, imp, ih);
  k_cast_cnorm<<<TT / 2 + CC / 4, 256, 0, stream>>>(x, xh, imp, cnorm);
  k_dist_top2<<<dim3(TT / 128, SPLITC), 256, 0, stream>>>(xh, ih, cnorm, bval, bidx);
  k_epilogue<<<TT / 4, 256, 0, stream>>>(x, imp, cnorm, bval, bidx, out_q, out_idx, rloss);
  k_loss_final<<<1, 256, 0, stream>>>(rloss, out_loss);
}

// Round 6
// 390.452 us; speedup vs baseline: 1.0830x; 1.0830x over previous
//
#include <hip/hip_runtime.h>
#include <cstdint>
#include <cstddef>

#define DD 512
#define TT 16384
#define CC 8192
#define RT 256              // dist: rows per block
#define CT 128              // dist: codes per block
#define NSPLIT (CC / CT)    // 64 slots per row
#define EPS_DIV 1e-6f
#define EPS_NORM 1e-12f
#define EPS_PD 1e-6f

typedef _Float16 half8 __attribute__((ext_vector_type(8)));
typedef _Float16 half4 __attribute__((ext_vector_type(4)));
typedef float floatx4 __attribute__((ext_vector_type(4)));

// async global->LDS, 16B per lane; lds base must be wave-uniform
#define GLDS16(g, l) __builtin_amdgcn_global_load_lds( \
    (const __attribute__((address_space(1))) void*)(g), \
    (__attribute__((address_space(3))) void*)(l), 16, 0, 0)

// ---------------- prep: split cb and W fp32 -> (hi|lo) fp16 [row][1024] ----------------
__global__ __launch_bounds__(256) void k_prep(
    const float* __restrict__ cb, const float* __restrict__ W,
    _Float16* __restrict__ cbs, _Float16* __restrict__ Ws) {
  const int b = blockIdx.x;
  const float* src;
  _Float16* dst;
  int row;
  if (b < CC / 2) {
    row = b * 2 + (threadIdx.x >> 7);
    src = cb; dst = cbs;
  } else {
    row = (b - CC / 2) * 2 + (threadIdx.x >> 7);
    src = W; dst = Ws;
  }
  const int col = (threadIdx.x & 127) * 4;
  float4 v = *(const float4*)(src + (size_t)row * DD + col);
  half4 h, l;
  h.x = (_Float16)v.x; l.x = (_Float16)(v.x - (float)h.x);
  h.y = (_Float16)v.y; l.y = (_Float16)(v.y - (float)h.y);
  h.z = (_Float16)v.z; l.z = (_Float16)(v.z - (float)h.z);
  h.w = (_Float16)v.w; l.w = (_Float16)(v.w - (float)h.w);
  *(half4*)(dst + (size_t)row * 1024 + col) = h;
  *(half4*)(dst + (size_t)row * 1024 + 512 + col) = l;
}

// ---------------- imp = cb @ W^T via split-fp16 3-pass MFMA ----------------
// 128x128 tile, 4 waves 2x2, BK=64 dbuf; coalesced LDS-transpose epilogue
// writes imp fp32 + ih fp16 + per-(row, d-block) norm partials.
__global__ __launch_bounds__(256) void k_gemm_mfma(
    const _Float16* __restrict__ cbs, const _Float16* __restrict__ Ws,
    float* __restrict__ imp, _Float16* __restrict__ ih,
    float* __restrict__ cnp) {
  __shared__ __align__(16) char smem[65536];  // A0,B0,A1,B1 @16KB; Csh 64KB overlaps
  const int tid = threadIdx.x;
  const int w = tid >> 6, lane = tid & 63;
  const int quad = lane >> 4, l15 = lane & 15;
  const int wm = (w & 1) * 64, wn = (w >> 1) * 64;
  const int c0 = blockIdx.x * 128;
  const int n0 = blockIdx.y * 128;

  const int srow8 = lane >> 3;
  const int scol = ((lane & 7) ^ srow8) << 3;  // halfs, XOR-swizzled col block
  size_t arow[4], brow[4];
#pragma unroll
  for (int j = 0; j < 4; ++j) {
    arow[j] = (size_t)(c0 + j * 32 + w * 8 + srow8) * 1024 + scol;
    brow[j] = (size_t)(n0 + j * 32 + w * 8 + srow8) * 1024 + scol;
  }
  int aoff[4], boff[4];
#pragma unroll
  for (int i = 0; i < 4; ++i) {
    aoff[i] = ((wm + i * 16 + l15) * 64 + ((quad ^ (l15 & 7)) << 3)) * 2;
    boff[i] = ((wn + i * 16 + l15) * 64 + ((quad ^ (l15 & 7)) << 3)) * 2;
  }

  auto stage = [&](int buf, int ak, int bk) {
    char* ab = smem + buf * 32768;
    char* bb = ab + 16384;
#pragma unroll
    for (int j = 0; j < 4; ++j) {
      GLDS16(cbs + arow[j] + ak, (_Float16*)ab + (j * 32 + w * 8) * 64);
      GLDS16(Ws  + brow[j] + bk, (_Float16*)bb + (j * 32 + w * 8) * 64);
    }
  };

  floatx4 acc[4][4] = {};
  stage(0, 0, 0);
#pragma unroll 2
  for (int it = 0; it < 24; ++it) {   // 3 passes x 8 k-steps
    __syncthreads();
    if (it < 23) {
      const int n = it + 1;
      const int p = n >> 3, kk = n & 7;
      const int ak = ((p == 2) ? 512 : 0) + kk * 64;
      const int bk = ((p == 1) ? 512 : 0) + kk * 64;
      stage(n & 1, ak, bk);
    }
    const char* ab = smem + (it & 1) * 32768;
    const char* bb = ab + 16384;
#pragma unroll
    for (int ks = 0; ks < 2; ++ks) {
      const int kx = ks * 64;
      half8 a[4], b[4];
#pragma unroll
      for (int mi = 0; mi < 4; ++mi)
        a[mi] = *(const half8*)(ab + (aoff[mi] ^ kx));
#pragma unroll
      for (int ni = 0; ni < 4; ++ni)
        b[ni] = *(const half8*)(bb + (boff[ni] ^ kx));
#pragma unroll
      for (int mi = 0; mi < 4; ++mi)
#pragma unroll
        for (int ni = 0; ni < 4; ++ni)
          acc[mi][ni] = __builtin_amdgcn_mfma_f32_16x16x32_f16(
              a[mi], b[ni], acc[mi][ni], 0, 0, 0);
    }
  }
  // epilogue: C fragments -> swizzled LDS tile -> coalesced stores + norm partials
  __syncthreads();
  float* Csh = (float*)smem;  // [128][128], col ^ ((row&7)<<2)
#pragma unroll
  for (int mi = 0; mi < 4; ++mi)
#pragma unroll
    for (int r = 0; r < 4; ++r) {
      const int row = wm + mi * 16 + quad * 4 + r;
      const int key = (row & 7) << 2;
#pragma unroll
      for (int ni = 0; ni < 4; ++ni) {
        const int col = wn + ni * 16 + l15;
        Csh[row * 128 + (col ^ key)] = acc[mi][ni][r];
      }
    }
  __syncthreads();
#pragma unroll
  for (int i = 0; i < 16; ++i) {
    const int row = (tid >> 5) * 16 + i;
    const int col = (tid & 31) * 4;
    const int key = (row & 7) << 2;
    const float4 v = *(const float4*)&Csh[row * 128 + (col ^ key)];
    *(float4*)&imp[(size_t)(c0 + row) * DD + n0 + col] = v;
    half4 h;
    h.x = (_Float16)v.x; h.y = (_Float16)v.y;
    h.z = (_Float16)v.z; h.w = (_Float16)v.w;
    *(half4*)&ih[(size_t)(c0 + row) * DD + n0 + col] = h;
    float ss = v.x * v.x + v.y * v.y + v.z * v.z + v.w * v.w;
#pragma unroll
    for (int m = 1; m < 32; m <<= 1) ss += __shfl_xor(ss, m);
    if ((tid & 31) == 0) cnp[(size_t)(n0 >> 7) * CC + c0 + row] = ss;
  }
}

// ---------------- cast x -> fp16 AND reduce norm partials ----------------
__global__ __launch_bounds__(256) void k_cast_cnorm(
    const float* __restrict__ x, _Float16* __restrict__ xh,
    const float* __restrict__ cnp, float* __restrict__ cnorm) {
  const int b = blockIdx.x;
  if (b < TT / 2) {
    const size_t base = (size_t)b * 1024 + threadIdx.x * 4;
    float4 v = *(const float4*)(x + base);
    half4 h;
    h.x = (_Float16)v.x; h.y = (_Float16)v.y;
    h.z = (_Float16)v.z; h.w = (_Float16)v.w;
    *(half4*)(xh + base) = h;
  } else {
    const int row = (b - TT / 2) * 256 + threadIdx.x;
    cnorm[row] = cnp[row] + cnp[CC + row] + cnp[2 * CC + row] + cnp[3 * CC + row];
  }
}

// ---------------- phase 1: fp16 hi.hi MFMA scores + per-row TOP-2 ----------------
// 256x128 tile, 256 threads, 4 waves each owning a 64x128 wave-tile
// (4 mi x 8 ni of 16x16x32), BK=32 dbuf (48KB LDS -> 2 blocks/CU).
// LDS layout k-major [kblk][row] -> frag reads contiguous, no swizzle needed.
__global__ __launch_bounds__(256, 2) void k_dist_top2(
    const _Float16* __restrict__ xh, const _Float16* __restrict__ ih,
    const float* __restrict__ cnorm,
    float* __restrict__ bval, int* __restrict__ bidx) {
  __shared__ __align__(16) char smem[49152];  // buf0 24KB | buf1 24KB; reduce 32KB overlaps
  const int tid = threadIdx.x;
  const int mw = tid >> 6, lane = tid & 63;
  const int quad = lane >> 4, l15 = lane & 15;
  const int r0 = blockIdx.x * RT;
  const int c0 = blockIdx.y * CT;

  // staging: A round r stages kblk r for row=tid; B round r stages kblks {2r,2r+1}
  const _Float16* gA = xh + (size_t)(r0 + tid) * DD;
  const _Float16* gB = ih + (size_t)(c0 + (tid & 127)) * DD + (tid >> 7) * 8;

  int aoff[4], boff[8];
#pragma unroll
  for (int mi = 0; mi < 4; ++mi)
    aoff[mi] = quad * 4096 + (mw * 64 + mi * 16 + l15) * 16;
#pragma unroll
  for (int ni = 0; ni < 8; ++ni)
    boff[ni] = quad * 2048 + (ni * 16 + l15) * 16;

  auto stage = [&](int s) {
    char* ab = smem + (s & 1) * 24576;
    char* bb = ab + 16384;
    const int k0 = s * 32;
#pragma unroll
    for (int r = 0; r < 4; ++r)   // A: 16KB, [kblk 4][row 256]
      GLDS16(gA + k0 + r * 8, ab + (r * 256 + mw * 64) * 16);
#pragma unroll
    for (int r = 0; r < 2; ++r)   // B: 8KB, [kblk 4][col 128]
      GLDS16(gB + k0 + r * 16, bb + (r * 256 + mw * 64) * 16);
  };

  floatx4 acc[4][8] = {};
  stage(0);
#pragma unroll 2
  for (int s = 0; s < 16; ++s) {
    __syncthreads();
    if (s < 15) stage(s + 1);
    const char* ab = smem + (s & 1) * 24576;
    const char* bb = ab + 16384;
    half8 a[4], b[8];
#pragma unroll
    for (int mi = 0; mi < 4; ++mi) a[mi] = *(const half8*)(ab + aoff[mi]);
#pragma unroll
    for (int ni = 0; ni < 8; ++ni) b[ni] = *(const half8*)(bb + boff[ni]);
#pragma unroll
    for (int mi = 0; mi < 4; ++mi)
#pragma unroll
      for (int ni = 0; ni < 8; ++ni)
        acc[mi][ni] = __builtin_amdgcn_mfma_f32_16x16x32_f16(
            a[mi], b[ni], acc[mi][ni], 0, 0, 0);
  }
  // fold 8 ni per slot (c ascends with ni; strict < keeps lowest idx)
  float cn[8];
#pragma unroll
  for (int ni = 0; ni < 8; ++ni) cn[ni] = cnorm[c0 + ni * 16 + l15];
  float best[16];
  int bsti[16];
#pragma unroll
  for (int mi = 0; mi < 4; ++mi)
#pragma unroll
    for (int r = 0; r < 4; ++r) {
      const int sl = mi * 4 + r;
      best[sl] = 3.4e38f; bsti[sl] = 0;
#pragma unroll
      for (int ni = 0; ni < 8; ++ni) {
        const float v = fmaf(-2.0f, acc[mi][ni][r], cn[ni]);
        if (v < best[sl]) { best[sl] = v; bsti[sl] = c0 + ni * 16 + l15; }
      }
    }
  // per-row top-2 over 16 lane-entries (LDS scratch overlaps tile buffers)
  __syncthreads();
  float* rv = (float*)smem;            // [256][16]
  int* ri = (int*)(smem + 16384);      // [256][16]
#pragma unroll
  for (int mi = 0; mi < 4; ++mi)
#pragma unroll
    for (int r = 0; r < 4; ++r) {
      const int rowl = mw * 64 + mi * 16 + quad * 4 + r;
      rv[rowl * 16 + l15] = best[mi * 4 + r];
      ri[rowl * 16 + l15] = bsti[mi * 4 + r];
    }
  __syncthreads();
  {
    const int row = tid;   // 256 threads, 256 rows
    float v1 = 3.4e38f, v2 = 3.4e38f;
    int i1 = 0x7fffffff, i2 = 0x7fffffff;
#pragma unroll
    for (int t = 0; t < 16; ++t) {
      const float v = rv[row * 16 + t];
      const int i = ri[row * 16 + t];
      if (v < v1 || (v == v1 && i < i1)) {
        v2 = v1; i2 = i1; v1 = v; i1 = i;
      } else if (v < v2 || (v == v2 && i < i2)) {
        v2 = v; i2 = i;
      }
    }
    const size_t o = ((size_t)blockIdx.y * TT + r0 + row) * 2;
    bval[o] = v1; bval[o + 1] = v2;
    bidx[o] = i1; bidx[o + 1] = i2;
  }
}

// ---------------- epilogue: butterfly top-2 merge, exact rescore, rotation ----------------
__global__ __launch_bounds__(256) void k_epilogue(
    const float* __restrict__ x, const float* __restrict__ imp,
    const float* __restrict__ cnorm,
    const float* __restrict__ bval, const int* __restrict__ bidx,
    float* __restrict__ outq, float* __restrict__ outidx,
    float* __restrict__ rloss) {
  const int lane = threadIdx.x & 63;
  const int row = blockIdx.x * 4 + (threadIdx.x >> 6);
  // lane l holds slot l's sorted top-2; 6-stage butterfly -> global top-2 everywhere
  const size_t o = ((size_t)lane * TT + row) * 2;
  float v1 = bval[o], v2 = bval[o + 1];
  int i1 = bidx[o], i2 = bidx[o + 1];
#pragma unroll
  for (int m = 1; m < 64; m <<= 1) {
    const float w1 = __shfl_xor(v1, m), w2 = __shfl_xor(v2, m);
    const int j1 = __shfl_xor(i1, m), j2 = __shfl_xor(i2, m);
    if (w1 < v1 || (w1 == v1 && j1 < i1)) {
      if (v1 < w2 || (v1 == w2 && i1 < j2)) { v2 = v1; i2 = i1; }
      else { v2 = w2; i2 = j2; }
      v1 = w1; i1 = j1;
    } else {
      if (w1 < v2 || (w1 == v2 && j1 < i2)) { v2 = w1; i2 = j1; }
    }
  }
  // exact fp32 rescore of both candidates
  const float* xr = x + (size_t)row * DD + lane * 8;
  float e[8], qa[8], qb[8];
  *(float4*)&e[0] = *(const float4*)xr;
  *(float4*)&e[4] = *(const float4*)(xr + 4);
  const float* q1p = imp + (size_t)i1 * DD + lane * 8;
  const float* q2p = imp + (size_t)i2 * DD + lane * 8;
  *(float4*)&qa[0] = *(const float4*)q1p;
  *(float4*)&qa[4] = *(const float4*)(q1p + 4);
  *(float4*)&qb[0] = *(const float4*)q2p;
  *(float4*)&qb[4] = *(const float4*)(q2p + 4);
  float d1 = 0.f, d2 = 0.f;
#pragma unroll
  for (int k = 0; k < 8; ++k) {
    d1 = fmaf(e[k], qa[k], d1);
    d2 = fmaf(e[k], qb[k], d2);
  }
#pragma unroll
  for (int m = 1; m < 64; m <<= 1) {
    d1 += __shfl_xor(d1, m);
    d2 += __shfl_xor(d2, m);
  }
  const float s1 = fmaf(-2.0f, d1, cnorm[i1]);
  const float s2 = fmaf(-2.0f, d2, cnorm[i2]);
  const bool use2 = (s2 < s1) || (s2 == s1 && i2 < i1);
  const int idx = use2 ? i2 : i1;
  float q[8];
#pragma unroll
  for (int k = 0; k < 8; ++k) q[k] = use2 ? qb[k] : qa[k];

  float xx = 0.f, qq = 0.f, xq = 0.f, cl = 0.f;
#pragma unroll
  for (int k = 0; k < 8; ++k) {
    xx = fmaf(e[k], e[k], xx);
    qq = fmaf(q[k], q[k], qq);
    xq = fmaf(e[k], q[k], xq);
    float d = e[k] - q[k] + EPS_PD;
    cl = fmaf(d, d, cl);
  }
#pragma unroll
  for (int m = 1; m < 64; m <<= 1) {
    xx += __shfl_xor(xx, m);
    qq += __shfl_xor(qq, m);
    xq += __shfl_xor(xq, m);
    cl += __shfl_xor(cl, m);
  }
  const float nx = sqrtf(xx), nq = sqrtf(qq);
  const float dx = fmaxf(nx, EPS_DIV), dq = fmaxf(nq, EPS_DIV);
  const float uu = xx / (dx * dx);
  const float qq2 = qq / (dq * dq);
  const float uq = xq / (dx * dq);
  const float ss = uu + qq2 + 2.0f * uq;
  const float dn = fmaxf(sqrtf(ss), EPS_NORM);
  const float es = xx / dx + xq / dq;
  const float a = 2.0f * es / (dn * dn);
  const float b = 2.0f * (xx / dx);
  const float scale = nq / dx;

  float ov[8];
#pragma unroll
  for (int k = 0; k < 8; ++k) {
    const float qp = q[k] / dq;
    const float sk = e[k] / dx + qp;
    ov[k] = (e[k] - a * sk + b * qp) * scale;
  }
  float* op = outq + (size_t)row * DD + lane * 8;
  *(float4*)op = *(const float4*)&ov[0];
  *(float4*)(op + 4) = *(const float4*)&ov[4];
  if (lane == 0) {
    outidx[row] = (float)idx;
    rloss[row] = cl;
  }
}

// ---------------- final loss reduction (deterministic) ----------------
__global__ __launch_bounds__(256) void k_loss_final(
    const float* __restrict__ rloss, float* __restrict__ out) {
  __shared__ double red[256];
  const int tid = threadIdx.x;
  double s = 0.0;
  for (int i = tid; i < TT; i += 256) s += (double)rloss[i];
  red[tid] = s;
  __syncthreads();
  for (int st = 128; st > 0; st >>= 1) {
    if (tid < st) red[tid] += red[tid + st];
    __syncthreads();
  }
  if (tid == 0) out[0] = (float)(red[0] / (double)TT);
}

extern "C" void kernel_launch(void* const* d_in, const int* in_sizes, int n_in,
                              void* d_out, int out_size, void* d_ws, size_t ws_size,
                              hipStream_t stream) {
  const float* x  = (const float*)d_in[0];   // [TT, DD]
  const float* W  = (const float*)d_in[1];   // [DD, DD]
  const float* cb = (const float*)d_in[2];   // [CC, DD]
  float* out = (float*)d_out;

  // workspace (~58 MiB); xh aliases cbs (cbs dead after k_gemm_mfma)
  float* imp = (float*)d_ws;                             // CC*DD fp32 (16 MiB)
  _Float16* ih = (_Float16*)(imp + (size_t)CC * DD);     // CC*DD f16 (8 MiB)
  _Float16* cbs = ih + (size_t)CC * DD;                  // CC*1024 f16 (16 MiB)
  _Float16* xh = cbs;                                    // TT*DD f16 (alias)
  _Float16* Ws = cbs + (size_t)CC * 1024;                // DD*1024 f16 (1 MiB)
  float* cnp   = (float*)(Ws + (size_t)DD * 1024);       // 4*CC
  float* cnorm = cnp + 4 * CC;                           // CC
  float* bval  = cnorm + CC;                             // NSPLIT*TT*2 (8 MiB)
  int*   bidx  = (int*)(bval + (size_t)NSPLIT * TT * 2); // 8 MiB
  float* rloss = (float*)(bidx + (size_t)NSPLIT * TT * 2);

  float* out_q    = out;
  float* out_idx  = out + (size_t)TT * DD;
  float* out_loss = out_idx + TT;

  k_prep<<<CC / 2 + DD / 2, 256, 0, stream>>>(cb, W, cbs, Ws);
  k_gemm_mfma<<<dim3(CC / 128, DD / 128), 256, 0, stream>>>(cbs, Ws, imp, ih, cnp);
  k_cast_cnorm<<<TT / 2 + CC / 256, 256, 0, stream>>>(x, xh, cnp, cnorm);
  k_dist_top2<<<dim3(TT / RT, CC / CT), 256, 0, stream>>>(xh, ih, cnorm, bval, bidx);
  k_epilogue<<<TT / 4, 256, 0, stream>>>(x, imp, cnorm, bval, bidx, out_q, out_idx, rloss);
  k_loss_final<<<1, 256, 0, stream>>>(rloss, out_loss);
}

// Round 7
// 373.317 us; speedup vs baseline: 1.1327x; 1.0459x over previous
//
#include <hip/hip_runtime.h>
#include <cstdint>
#include <cstddef>

#define DD 512
#define TT 16384
#define CC 8192
#define RT 256              // dist: rows per block
#define CT 128              // dist: codes per block
#define NSPLIT (CC / CT)    // 64 slots per row
#define EPS_DIV 1e-6f
#define EPS_NORM 1e-12f
#define EPS_PD 1e-6f

typedef _Float16 half8 __attribute__((ext_vector_type(8)));
typedef _Float16 half4 __attribute__((ext_vector_type(4)));
typedef float floatx4 __attribute__((ext_vector_type(4)));

// async global->LDS, 16B per lane; lds base must be wave-uniform
#define GLDS16(g, l) __builtin_amdgcn_global_load_lds( \
    (const __attribute__((address_space(1))) void*)(g), \
    (__attribute__((address_space(3))) void*)(l), 16, 0, 0)

// ---------------- prep: split cb/W -> (hi|lo) fp16 [row][1024]; cast x -> k-major fp16 ----------------
// xh_t layout: [kblk 16][row TT][32 halfs]
__global__ __launch_bounds__(256) void k_prep(
    const float* __restrict__ cb, const float* __restrict__ W,
    const float* __restrict__ x,
    _Float16* __restrict__ cbs, _Float16* __restrict__ Ws,
    _Float16* __restrict__ xh_t) {
  const int b = blockIdx.x;
  if (b < CC / 2 + DD / 2) {
    const float* src;
    _Float16* dst;
    int row;
    if (b < CC / 2) {
      row = b * 2 + (threadIdx.x >> 7);
      src = cb; dst = cbs;
    } else {
      row = (b - CC / 2) * 2 + (threadIdx.x >> 7);
      src = W; dst = Ws;
    }
    const int col = (threadIdx.x & 127) * 4;
    float4 v = *(const float4*)(src + (size_t)row * DD + col);
    half4 h, l;
    h.x = (_Float16)v.x; l.x = (_Float16)(v.x - (float)h.x);
    h.y = (_Float16)v.y; l.y = (_Float16)(v.y - (float)h.y);
    h.z = (_Float16)v.z; l.z = (_Float16)(v.z - (float)h.z);
    h.w = (_Float16)v.w; l.w = (_Float16)(v.w - (float)h.w);
    *(half4*)(dst + (size_t)row * 1024 + col) = h;
    *(half4*)(dst + (size_t)row * 1024 + 512 + col) = l;
  } else {
    const int b2 = b - (CC / 2 + DD / 2);
    const int row = b2 * 2 + (threadIdx.x >> 7);
    const int col = (threadIdx.x & 127) * 4;
    float4 v = *(const float4*)(x + (size_t)row * DD + col);
    half4 h;
    h.x = (_Float16)v.x; h.y = (_Float16)v.y;
    h.z = (_Float16)v.z; h.w = (_Float16)v.w;
    const int p = col >> 5, off = col & 31;
    *(half4*)(xh_t + ((size_t)p * TT + row) * 32 + off) = h;
  }
}

// ---------------- imp = cb @ W^T via split-fp16 3-pass MFMA ----------------
// 128x128 tile, 4 waves 2x2, BK=64 dbuf; coalesced LDS-transpose epilogue
// writes imp fp32 + ih_t fp16 (k-major [kblk][code][32]) + norm partials cnp.
__global__ __launch_bounds__(256) void k_gemm_mfma(
    const _Float16* __restrict__ cbs, const _Float16* __restrict__ Ws,
    float* __restrict__ imp, _Float16* __restrict__ ih_t,
    float* __restrict__ cnp) {
  __shared__ __align__(16) char smem[65536];  // A0,B0,A1,B1 @16KB; Csh 64KB overlaps
  const int tid = threadIdx.x;
  const int w = tid >> 6, lane = tid & 63;
  const int quad = lane >> 4, l15 = lane & 15;
  const int wm = (w & 1) * 64, wn = (w >> 1) * 64;
  const int c0 = blockIdx.x * 128;
  const int n0 = blockIdx.y * 128;

  const int srow8 = lane >> 3;
  const int scol = ((lane & 7) ^ srow8) << 3;  // halfs, XOR-swizzled col block
  size_t arow[4], brow[4];
#pragma unroll
  for (int j = 0; j < 4; ++j) {
    arow[j] = (size_t)(c0 + j * 32 + w * 8 + srow8) * 1024 + scol;
    brow[j] = (size_t)(n0 + j * 32 + w * 8 + srow8) * 1024 + scol;
  }
  int aoff[4], boff[4];
#pragma unroll
  for (int i = 0; i < 4; ++i) {
    aoff[i] = ((wm + i * 16 + l15) * 64 + ((quad ^ (l15 & 7)) << 3)) * 2;
    boff[i] = ((wn + i * 16 + l15) * 64 + ((quad ^ (l15 & 7)) << 3)) * 2;
  }

  auto stage = [&](int buf, int ak, int bk) {
    char* ab = smem + buf * 32768;
    char* bb = ab + 16384;
#pragma unroll
    for (int j = 0; j < 4; ++j) {
      GLDS16(cbs + arow[j] + ak, (_Float16*)ab + (j * 32 + w * 8) * 64);
      GLDS16(Ws  + brow[j] + bk, (_Float16*)bb + (j * 32 + w * 8) * 64);
    }
  };

  floatx4 acc[4][4] = {};
  stage(0, 0, 0);
#pragma unroll 2
  for (int it = 0; it < 24; ++it) {   // 3 passes x 8 k-steps
    __syncthreads();
    if (it < 23) {
      const int n = it + 1;
      const int p = n >> 3, kk = n & 7;
      const int ak = ((p == 2) ? 512 : 0) + kk * 64;
      const int bk = ((p == 1) ? 512 : 0) + kk * 64;
      stage(n & 1, ak, bk);
    }
    const char* ab = smem + (it & 1) * 32768;
    const char* bb = ab + 16384;
#pragma unroll
    for (int ks = 0; ks < 2; ++ks) {
      const int kx = ks * 64;
      half8 a[4], b[4];
#pragma unroll
      for (int mi = 0; mi < 4; ++mi)
        a[mi] = *(const half8*)(ab + (aoff[mi] ^ kx));
#pragma unroll
      for (int ni = 0; ni < 4; ++ni)
        b[ni] = *(const half8*)(bb + (boff[ni] ^ kx));
#pragma unroll
      for (int mi = 0; mi < 4; ++mi)
#pragma unroll
        for (int ni = 0; ni < 4; ++ni)
          acc[mi][ni] = __builtin_amdgcn_mfma_f32_16x16x32_f16(
              a[mi], b[ni], acc[mi][ni], 0, 0, 0);
    }
  }
  // epilogue: C fragments -> swizzled LDS tile -> coalesced stores + norm partials
  __syncthreads();
  float* Csh = (float*)smem;  // [128][128], col ^ ((row&7)<<2)
#pragma unroll
  for (int mi = 0; mi < 4; ++mi)
#pragma unroll
    for (int r = 0; r < 4; ++r) {
      const int row = wm + mi * 16 + quad * 4 + r;
      const int key = (row & 7) << 2;
#pragma unroll
      for (int ni = 0; ni < 4; ++ni) {
        const int col = wn + ni * 16 + l15;
        Csh[row * 128 + (col ^ key)] = acc[mi][ni][r];
      }
    }
  __syncthreads();
#pragma unroll
  for (int i = 0; i < 16; ++i) {
    const int row = (tid >> 5) * 16 + i;     // local code index
    const int col = (tid & 31) * 4;          // local d index
    const int key = (row & 7) << 2;
    const float4 v = *(const float4*)&Csh[row * 128 + (col ^ key)];
    *(float4*)&imp[(size_t)(c0 + row) * DD + n0 + col] = v;
    half4 h;
    h.x = (_Float16)v.x; h.y = (_Float16)v.y;
    h.z = (_Float16)v.z; h.w = (_Float16)v.w;
    const int d = n0 + col;
    const int p = d >> 5, off = d & 31;
    *(half4*)(ih_t + ((size_t)p * CC + c0 + row) * 32 + off) = h;
    float ss = v.x * v.x + v.y * v.y + v.z * v.z + v.w * v.w;
#pragma unroll
    for (int m = 1; m < 32; m <<= 1) ss += __shfl_xor(ss, m);
    if ((tid & 31) == 0) cnp[(size_t)(n0 >> 7) * CC + c0 + row] = ss;
  }
}

// ---------------- phase 1: barrier-free direct-load MFMA scores + per-row TOP-2 ----------------
// 256x128 tile, 4 waves each owning 64x128. Operands are k-major so every
// fragment load is a fully-coalesced global_load_dwordx4 straight to VGPRs.
// No LDS staging, no K-loop barriers; unroll-2 gives register double-buffering.
__global__ __launch_bounds__(256, 2) void k_dist_top2(
    const _Float16* __restrict__ xh_t, const _Float16* __restrict__ ih_t,
    const float* __restrict__ cnp,
    float* __restrict__ bval, int* __restrict__ bidx) {
  __shared__ float rv[256 * 16];
  __shared__ int   ri[256 * 16];
  const int tid = threadIdx.x;
  const int mw = tid >> 6, lane = tid & 63;
  const int quad = lane >> 4, l15 = lane & 15;
  const int r0 = blockIdx.x * RT;
  const int c0 = blockIdx.y * CT;

  const char* pa = (const char*)xh_t;
  const char* pb = (const char*)ih_t;
  int voa[4], vob[8];
#pragma unroll
  for (int mi = 0; mi < 4; ++mi)
    voa[mi] = ((r0 + mw * 64 + mi * 16 + l15) * 32 + quad * 8) * 2;
#pragma unroll
  for (int ni = 0; ni < 8; ++ni)
    vob[ni] = ((c0 + ni * 16 + l15) * 32 + quad * 8) * 2;

  floatx4 acc[4][8] = {};
#pragma unroll 2
  for (int s = 0; s < 16; ++s) {
    const char* sa = pa + (size_t)s * (TT * 64);
    const char* sb = pb + (size_t)s * (CC * 64);
    half8 a[4], b[8];
#pragma unroll
    for (int mi = 0; mi < 4; ++mi) a[mi] = *(const half8*)(sa + voa[mi]);
#pragma unroll
    for (int ni = 0; ni < 8; ++ni) b[ni] = *(const half8*)(sb + vob[ni]);
#pragma unroll
    for (int mi = 0; mi < 4; ++mi)
#pragma unroll
      for (int ni = 0; ni < 8; ++ni)
        acc[mi][ni] = __builtin_amdgcn_mfma_f32_16x16x32_f16(
            a[mi], b[ni], acc[mi][ni], 0, 0, 0);
  }
  // cnorm for this block's 128 codes, from 4 d-block partials
  float cn[8];
#pragma unroll
  for (int ni = 0; ni < 8; ++ni) {
    const int c = c0 + ni * 16 + l15;
    cn[ni] = cnp[c] + cnp[CC + c] + cnp[2 * CC + c] + cnp[3 * CC + c];
  }
  // fold 8 ni per slot (c ascends with ni; strict < keeps lowest idx)
  float best[16];
  int bsti[16];
#pragma unroll
  for (int mi = 0; mi < 4; ++mi)
#pragma unroll
    for (int r = 0; r < 4; ++r) {
      const int sl = mi * 4 + r;
      best[sl] = 3.4e38f; bsti[sl] = 0;
#pragma unroll
      for (int ni = 0; ni < 8; ++ni) {
        const float v = fmaf(-2.0f, acc[mi][ni][r], cn[ni]);
        if (v < best[sl]) { best[sl] = v; bsti[sl] = c0 + ni * 16 + l15; }
      }
    }
  // per-row top-2 over 16 lane-entries
  __syncthreads();
#pragma unroll
  for (int mi = 0; mi < 4; ++mi)
#pragma unroll
    for (int r = 0; r < 4; ++r) {
      const int rowl = mw * 64 + mi * 16 + quad * 4 + r;
      rv[rowl * 16 + l15] = best[mi * 4 + r];
      ri[rowl * 16 + l15] = bsti[mi * 4 + r];
    }
  __syncthreads();
  {
    const int row = tid;   // 256 threads, 256 rows
    float v1 = 3.4e38f, v2 = 3.4e38f;
    int i1 = 0x7fffffff, i2 = 0x7fffffff;
#pragma unroll
    for (int t = 0; t < 16; ++t) {
      const float v = rv[row * 16 + t];
      const int i = ri[row * 16 + t];
      if (v < v1 || (v == v1 && i < i1)) {
        v2 = v1; i2 = i1; v1 = v; i1 = i;
      } else if (v < v2 || (v == v2 && i < i2)) {
        v2 = v; i2 = i;
      }
    }
    const size_t o = ((size_t)blockIdx.y * TT + r0 + row) * 2;
    bval[o] = v1; bval[o + 1] = v2;
    bidx[o] = i1; bidx[o + 1] = i2;
  }
}

// ---------------- epilogue: butterfly top-2 merge, exact rescore, rotation ----------------
__global__ __launch_bounds__(256) void k_epilogue(
    const float* __restrict__ x, const float* __restrict__ imp,
    const float* __restrict__ cnp,
    const float* __restrict__ bval, const int* __restrict__ bidx,
    float* __restrict__ outq, float* __restrict__ outidx,
    float* __restrict__ rloss) {
  const int lane = threadIdx.x & 63;
  const int row = blockIdx.x * 4 + (threadIdx.x >> 6);
  // lane l holds slot l's sorted top-2; 6-stage butterfly -> global top-2 everywhere
  const size_t o = ((size_t)lane * TT + row) * 2;
  float v1 = bval[o], v2 = bval[o + 1];
  int i1 = bidx[o], i2 = bidx[o + 1];
#pragma unroll
  for (int m = 1; m < 64; m <<= 1) {
    const float w1 = __shfl_xor(v1, m), w2 = __shfl_xor(v2, m);
    const int j1 = __shfl_xor(i1, m), j2 = __shfl_xor(i2, m);
    if (w1 < v1 || (w1 == v1 && j1 < i1)) {
      if (v1 < w2 || (v1 == w2 && i1 < j2)) { v2 = v1; i2 = i1; }
      else { v2 = w2; i2 = j2; }
      v1 = w1; i1 = j1;
    } else {
      if (w1 < v2 || (w1 == v2 && j1 < i2)) { v2 = w1; i2 = j1; }
    }
  }
  // exact fp32 rescore of both candidates
  const float* xr = x + (size_t)row * DD + lane * 8;
  float e[8], qa[8], qb[8];
  *(float4*)&e[0] = *(const float4*)xr;
  *(float4*)&e[4] = *(const float4*)(xr + 4);
  const float* q1p = imp + (size_t)i1 * DD + lane * 8;
  const float* q2p = imp + (size_t)i2 * DD + lane * 8;
  *(float4*)&qa[0] = *(const float4*)q1p;
  *(float4*)&qa[4] = *(const float4*)(q1p + 4);
  *(float4*)&qb[0] = *(const float4*)q2p;
  *(float4*)&qb[4] = *(const float4*)(q2p + 4);
  float d1 = 0.f, d2 = 0.f;
#pragma unroll
  for (int k = 0; k < 8; ++k) {
    d1 = fmaf(e[k], qa[k], d1);
    d2 = fmaf(e[k], qb[k], d2);
  }
#pragma unroll
  for (int m = 1; m < 64; m <<= 1) {
    d1 += __shfl_xor(d1, m);
    d2 += __shfl_xor(d2, m);
  }
  const float n1 = cnp[i1] + cnp[CC + i1] + cnp[2 * CC + i1] + cnp[3 * CC + i1];
  const float n2 = cnp[i2] + cnp[CC + i2] + cnp[2 * CC + i2] + cnp[3 * CC + i2];
  const float s1 = fmaf(-2.0f, d1, n1);
  const float s2 = fmaf(-2.0f, d2, n2);
  const bool use2 = (s2 < s1) || (s2 == s1 && i2 < i1);
  const int idx = use2 ? i2 : i1;
  float q[8];
#pragma unroll
  for (int k = 0; k < 8; ++k) q[k] = use2 ? qb[k] : qa[k];

  float xx = 0.f, qq = 0.f, xq = 0.f, cl = 0.f;
#pragma unroll
  for (int k = 0; k < 8; ++k) {
    xx = fmaf(e[k], e[k], xx);
    qq = fmaf(q[k], q[k], qq);
    xq = fmaf(e[k], q[k], xq);
    float d = e[k] - q[k] + EPS_PD;
    cl = fmaf(d, d, cl);
  }
#pragma unroll
  for (int m = 1; m < 64; m <<= 1) {
    xx += __shfl_xor(xx, m);
    qq += __shfl_xor(qq, m);
    xq += __shfl_xor(xq, m);
    cl += __shfl_xor(cl, m);
  }
  const float nx = sqrtf(xx), nq = sqrtf(qq);
  const float dx = fmaxf(nx, EPS_DIV), dq = fmaxf(nq, EPS_DIV);
  const float uu = xx / (dx * dx);
  const float qq2 = qq / (dq * dq);
  const float uq = xq / (dx * dq);
  const float ss = uu + qq2 + 2.0f * uq;
  const float dn = fmaxf(sqrtf(ss), EPS_NORM);
  const float es = xx / dx + xq / dq;
  const float a = 2.0f * es / (dn * dn);
  const float b = 2.0f * (xx / dx);
  const float scale = nq / dx;

  float ov[8];
#pragma unroll
  for (int k = 0; k < 8; ++k) {
    const float qp = q[k] / dq;
    const float sk = e[k] / dx + qp;
    ov[k] = (e[k] - a * sk + b * qp) * scale;
  }
  float* op = outq + (size_t)row * DD + lane * 8;
  *(float4*)op = *(const float4*)&ov[0];
  *(float4*)(op + 4) = *(const float4*)&ov[4];
  if (lane == 0) {
    outidx[row] = (float)idx;
    rloss[row] = cl;
  }
}

// ---------------- final loss reduction (deterministic) ----------------
__global__ __launch_bounds__(256) void k_loss_final(
    const float* __restrict__ rloss, float* __restrict__ out) {
  __shared__ double red[256];
  const int tid = threadIdx.x;
  double s = 0.0;
  for (int i = tid; i < TT; i += 256) s += (double)rloss[i];
  red[tid] = s;
  __syncthreads();
  for (int st = 128; st > 0; st >>= 1) {
    if (tid < st) red[tid] += red[tid + st];
    __syncthreads();
  }
  if (tid == 0) out[0] = (float)(red[0] / (double)TT);
}

extern "C" void kernel_launch(void* const* d_in, const int* in_sizes, int n_in,
                              void* d_out, int out_size, void* d_ws, size_t ws_size,
                              hipStream_t stream) {
  const float* x  = (const float*)d_in[0];   // [TT, DD]
  const float* W  = (const float*)d_in[1];   // [DD, DD]
  const float* cb = (const float*)d_in[2];   // [CC, DD]
  float* out = (float*)d_out;

  // workspace (~57 MiB); bval/bidx overlay cbs (dead after k_gemm_mfma)
  float* imp = (float*)d_ws;                             // CC*DD fp32 (16 MiB)
  _Float16* ih_t = (_Float16*)(imp + (size_t)CC * DD);   // CC*DD f16 k-major (8 MiB)
  _Float16* xh_t = ih_t + (size_t)CC * DD;               // TT*DD f16 k-major (16 MiB)
  _Float16* Ws = xh_t + (size_t)TT * DD;                 // DD*1024 f16 (1 MiB)
  float* cnp   = (float*)(Ws + (size_t)DD * 1024);       // 4*CC (128 KiB)
  float* rloss = cnp + 4 * CC;                           // TT (64 KiB)
  _Float16* cbs = (_Float16*)(rloss + TT);               // CC*1024 f16 (16 MiB)
  float* bval  = (float*)cbs;                            // NSPLIT*TT*2 (8 MiB, overlay)
  int*   bidx  = (int*)(bval + (size_t)NSPLIT * TT * 2); // 8 MiB (overlay)

  float* out_q    = out;
  float* out_idx  = out + (size_t)TT * DD;
  float* out_loss = out_idx + TT;

  k_prep<<<CC / 2 + DD / 2 + TT / 2, 256, 0, stream>>>(cb, W, x, cbs, Ws, xh_t);
  k_gemm_mfma<<<dim3(CC / 128, DD / 128), 256, 0, stream>>>(cbs, Ws, imp, ih_t, cnp);
  k_dist_top2<<<dim3(TT / RT, CC / CT), 256, 0, stream>>>(xh_t, ih_t, cnp, bval, bidx);
  k_epilogue<<<TT / 4, 256, 0, stream>>>(x, imp, cnp, bval, bidx, out_q, out_idx, rloss);
  k_loss_final<<<1, 256, 0, stream>>>(rloss, out_loss);
}